// Round 1
// baseline (710.108 us; speedup 1.0000x reference)
//
#include <hip/hip_runtime.h>
#include <math.h>

#define DEV static __device__ __forceinline__

DEV float rdlane(float v, int l) {
  return __int_as_float(__builtin_amdgcn_readlane(__float_as_int(v), l));
}

DEV float wave_sum64(float v) {
  v += __shfl_xor(v, 32, 64);
  v += __shfl_xor(v, 16, 64);
  v += __shfl_xor(v, 8, 64);
  v += __shfl_xor(v, 4, 64);
  v += __shfl_xor(v, 2, 64);
  v += __shfl_xor(v, 1, 64);
  return v;
}

// ---------------------------------------------------------------------------
// Kernel 1: items = bs*33.  j in [0,32): v1[b][j] (hop-1 aggregate of edge j).
//           j == 32       : v0_first[b] (hop-0 aggregate, same weights).
// One wave64 per item; lane = output feature dim d.
// LDS: w_ent0 (128x64) + w0 (192x64) = 80 KB.
// ---------------------------------------------------------------------------
__global__ __launch_bounds__(1024, 8)
void k_agg_hop(const int* __restrict__ relations, const int* __restrict__ entity_pairs,
               const int* __restrict__ train_edges,
               const int* __restrict__ entity2edges, const int* __restrict__ edge2entities,
               const int* __restrict__ edge2relation,
               const float* __restrict__ ent_emb, const float* __restrict__ rel_emb,
               const float* __restrict__ w_ent0, const float* __restrict__ b_ent0,
               const float* __restrict__ w0, const float* __restrict__ b0,
               float* __restrict__ v1ws, int n_items)
{
  extern __shared__ float Lw[];
  float* Lwe = Lw;            // 8192 floats (w_ent0: [128][64])
  float* Lw0 = Lw + 8192;     // 12288 floats (w0: [192][64])
  for (int t = threadIdx.x; t < 8192; t += blockDim.x) Lwe[t] = w_ent0[t];
  for (int t = threadIdx.x; t < 12288; t += blockDim.x) Lw0[t] = w0[t];
  __syncthreads();

  const int lane = threadIdx.x & 63;
  const int wid = threadIdx.x >> 6;
  const int wperb = blockDim.x >> 6;
  const float bent = b_ent0[lane];
  const float b0v = b0[lane];

  for (int item = blockIdx.x * wperb + wid; item < n_items;
       item += gridDim.x * wperb) {
    const int b = item / 33;
    const int j = item - b * 33;
    const int te = train_edges[b];

    int rsel, n0, n1;
    if (j < 32) {  // wave-uniform branch
      const int eself = entity2edges[entity_pairs[b * 2 + (j >> 4)] * 16 + (j & 15)];
      rsel = edge2relation[eself];
      n0 = edge2entities[eself * 2 + 0];
      n1 = edge2entities[eself * 2 + 1];
    } else {
      rsel = relations[b];
      n0 = entity_pairs[b * 2 + 0];
      n1 = entity_pairs[b * 2 + 1];
    }

    // --- masked-mean over the 2x16 neighbor edges' relation vectors ---
    // lanes 0..15 -> (c=0,s), 16..31 -> (c=1,s); lanes 32..63 duplicate.
    const int myent = ((lane >> 4) & 1) ? n1 : n0;
    const int e = entity2edges[myent * 16 + (lane & 15)];
    const unsigned long long bal = __ballot(e != te);
    const int r = edge2relation[e];
    const int cnt0 = __popcll(bal & 0xFFFFull);
    const int cnt1 = __popcll(bal & 0xFFFF0000ull);
    float acc0 = 0.f, acc1 = 0.f;
#pragma unroll
    for (int s = 0; s < 16; ++s) {
      const int rA = __builtin_amdgcn_readlane(r, s);
      const int rB = __builtin_amdgcn_readlane(r, s + 16);
      const float mA = (float)((bal >> s) & 1ull);
      const float mB = (float)((bal >> (s + 16)) & 1ull);
      acc0 = fmaf(mA, rel_emb[rA * 64 + lane], acc0);
      acc1 = fmaf(mB, rel_emb[rB * 64 + lane], acc1);
    }
    acc0 *= 1.0f / (float)(cnt0 ? cnt0 : 1);
    acc1 *= 1.0f / (float)(cnt1 ? cnt1 : 1);

    const float enA = ent_emb[n0 * 64 + lane];
    const float enB = ent_emb[n1 * 64 + lane];
    const float selfv = rel_emb[rsel * 64 + lane];

    // --- nv_c = [en_c, mean_c] @ w_ent0 + b_ent0  (two columns share weights)
    float nv0 = bent, nv1 = bent;
#pragma unroll
    for (int i = 0; i < 64; ++i) {
      const float wA = Lwe[i * 64 + lane];
      const float wB = Lwe[(64 + i) * 64 + lane];
      nv0 = fmaf(rdlane(enA, i), wA, nv0);
      nv1 = fmaf(rdlane(enB, i), wA, nv1);
      nv0 = fmaf(rdlane(acc0, i), wB, nv0);
      nv1 = fmaf(rdlane(acc1, i), wB, nv1);
    }

    // --- sv = [self, nv0, nv1] @ w0 + b0
    float sv = b0v;
#pragma unroll
    for (int i = 0; i < 64; ++i) {
      sv = fmaf(rdlane(selfv, i), Lw0[i * 64 + lane], sv);
      sv = fmaf(rdlane(nv0, i), Lw0[(64 + i) * 64 + lane], sv);
      sv = fmaf(rdlane(nv1, i), Lw0[(128 + i) * 64 + lane], sv);
    }
    v1ws[item * 64 + lane] = sv;
  }
}

// ---------------------------------------------------------------------------
// Kernel 2: one wave per batch element b.
// Second aggregation (w_ent1/w1 over v1 from ws) -> ctx, then K=10 attention
// + final score. LDS: w_ent1 + w1 + wq + wk + wv = 128 KB.
// ---------------------------------------------------------------------------
__global__ __launch_bounds__(256, 2)
void k_ctx_score(const int* __restrict__ entity_pairs, const int* __restrict__ train_edges,
                 const int* __restrict__ user_ids, const int* __restrict__ top_k_ids,
                 const int* __restrict__ entity2edges,
                 const float* __restrict__ ent_emb, const float* __restrict__ user_emb,
                 const float* __restrict__ w_ent1, const float* __restrict__ b_ent1,
                 const float* __restrict__ w1, const float* __restrict__ b1,
                 const float* __restrict__ wq, const float* __restrict__ bq,
                 const float* __restrict__ wk, const float* __restrict__ bk,
                 const float* __restrict__ wv, const float* __restrict__ bv,
                 const float* __restrict__ w_s, const float* __restrict__ b_s,
                 const float* __restrict__ v1ws, float* __restrict__ out, int bs)
{
  extern __shared__ float Lw[];
  float* Lwe = Lw;             // 8192  (w_ent1)
  float* Lw1 = Lw + 8192;      // 12288 (w1)
  float* Lwq = Lw + 20480;     // 4096
  float* Lwk = Lw + 24576;     // 4096
  float* Lwv = Lw + 28672;     // 4096
  for (int t = threadIdx.x; t < 8192; t += blockDim.x) Lwe[t] = w_ent1[t];
  for (int t = threadIdx.x; t < 12288; t += blockDim.x) Lw1[t] = w1[t];
  for (int t = threadIdx.x; t < 4096; t += blockDim.x) {
    Lwq[t] = wq[t]; Lwk[t] = wk[t]; Lwv[t] = wv[t];
  }
  __syncthreads();

  const int lane = threadIdx.x & 63;
  const int wid = threadIdx.x >> 6;
  const int b = blockIdx.x * (blockDim.x >> 6) + wid;
  if (b >= bs) return;

  const int te = train_edges[b];
  const int n0 = entity_pairs[b * 2 + 0];
  const int n1 = entity_pairs[b * 2 + 1];
  const int myent = ((lane >> 4) & 1) ? n1 : n0;
  const int e = entity2edges[myent * 16 + (lane & 15)];
  const unsigned long long bal = __ballot(e != te);
  const int cnt0 = __popcll(bal & 0xFFFFull);
  const int cnt1 = __popcll(bal & 0xFFFF0000ull);

  const float* vbase = v1ws + (size_t)b * 33 * 64;
  float acc0 = 0.f, acc1 = 0.f;
#pragma unroll
  for (int s = 0; s < 16; ++s) {
    const float mA = (float)((bal >> s) & 1ull);
    const float mB = (float)((bal >> (s + 16)) & 1ull);
    acc0 = fmaf(mA, vbase[s * 64 + lane], acc0);
    acc1 = fmaf(mB, vbase[(16 + s) * 64 + lane], acc1);
  }
  acc0 *= 1.0f / (float)(cnt0 ? cnt0 : 1);
  acc1 *= 1.0f / (float)(cnt1 ? cnt1 : 1);

  const float enA = ent_emb[n0 * 64 + lane];
  const float enB = ent_emb[n1 * 64 + lane];
  float nv0 = b_ent1[lane], nv1 = nv0;
#pragma unroll
  for (int i = 0; i < 64; ++i) {
    const float wA = Lwe[i * 64 + lane];
    const float wB = Lwe[(64 + i) * 64 + lane];
    nv0 = fmaf(rdlane(enA, i), wA, nv0);
    nv1 = fmaf(rdlane(enB, i), wA, nv1);
    nv0 = fmaf(rdlane(acc0, i), wB, nv0);
    nv1 = fmaf(rdlane(acc1, i), wB, nv1);
  }

  const float selfv = vbase[32 * 64 + lane];
  float ctx = b1[lane];
#pragma unroll
  for (int i = 0; i < 64; ++i) {
    ctx = fmaf(rdlane(selfv, i), Lw1[i * 64 + lane], ctx);
    ctx = fmaf(rdlane(nv0, i), Lw1[(64 + i) * 64 + lane], ctx);
    ctx = fmaf(rdlane(nv1, i), Lw1[(128 + i) * 64 + lane], ctx);
  }

  // ---- attention over K=10 candidates ----
  const float u = user_emb[user_ids[b] * 64 + lane];
  float q = bq[lane];
#pragma unroll
  for (int i = 0; i < 64; ++i) q = fmaf(rdlane(u, i), Lwq[i * 64 + lane], q);

  const float bkv = bk[lane], bvv = bv[lane];
  float lg[10], vv[10];
#pragma unroll
  for (int k = 0; k < 10; ++k) {
    const int tk_id = top_k_ids[b * 10 + k];
    const float tk = ent_emb[tk_id * 64 + lane];
    float kk = bkv, vk = bvv;
#pragma unroll
    for (int i = 0; i < 64; ++i) {
      const float xv = rdlane(tk, i);
      kk = fmaf(xv, Lwk[i * 64 + lane], kk);
      vk = fmaf(xv, Lwv[i * 64 + lane], vk);
    }
    lg[k] = wave_sum64(q * kk) * 0.125f;  // 1/sqrt(64)
    vv[k] = vk;
  }
  float m = lg[0];
#pragma unroll
  for (int k = 1; k < 10; ++k) m = fmaxf(m, lg[k]);
  float den = 0.f;
  float att[10];
#pragma unroll
  for (int k = 0; k < 10; ++k) { att[k] = expf(lg[k] - m); den += att[k]; }
  const float invden = 1.0f / den;
  float uatt = 0.f;
#pragma unroll
  for (int k = 0; k < 10; ++k) uatt = fmaf(att[k] * invden, vv[k], uatt);

  const float sc = wave_sum64(uatt * ctx + ctx * w_s[lane]);
  if (lane == 0) out[b] = sc + b_s[0];
}

extern "C" void kernel_launch(void* const* d_in, const int* in_sizes, int n_in,
                              void* d_out, int out_size, void* d_ws, size_t ws_size,
                              hipStream_t stream) {
  const int* relations     = (const int*)d_in[0];
  const int* entity_pairs  = (const int*)d_in[1];
  const int* train_edges   = (const int*)d_in[2];
  const int* user_ids      = (const int*)d_in[3];
  const int* top_k_ids     = (const int*)d_in[4];
  const int* entity2edges  = (const int*)d_in[5];
  const int* edge2entities = (const int*)d_in[6];
  const int* edge2relation = (const int*)d_in[7];
  const float* ent_emb  = (const float*)d_in[8];
  const float* rel_emb  = (const float*)d_in[9];
  const float* user_emb = (const float*)d_in[10];
  const float* w_ent0 = (const float*)d_in[11];
  const float* b_ent0 = (const float*)d_in[12];
  const float* w0     = (const float*)d_in[13];
  const float* b0     = (const float*)d_in[14];
  const float* w_ent1 = (const float*)d_in[15];
  const float* b_ent1 = (const float*)d_in[16];
  const float* w1     = (const float*)d_in[17];
  const float* b1     = (const float*)d_in[18];
  const float* wq  = (const float*)d_in[19];
  const float* bq  = (const float*)d_in[20];
  const float* wk  = (const float*)d_in[21];
  const float* bk  = (const float*)d_in[22];
  const float* wv  = (const float*)d_in[23];
  const float* bv  = (const float*)d_in[24];
  const float* w_s = (const float*)d_in[25];
  const float* b_s = (const float*)d_in[26];

  const int bs = in_sizes[0];
  const int n_items = bs * 33;
  float* v1ws = (float*)d_ws;  // n_items * 64 floats (~8.3 MB)

  k_agg_hop<<<dim3(512), dim3(1024), 20480 * sizeof(float), stream>>>(
      relations, entity_pairs, train_edges, entity2edges, edge2entities,
      edge2relation, ent_emb, rel_emb, w_ent0, b_ent0, w0, b0, v1ws, n_items);

  k_ctx_score<<<dim3((bs + 3) / 4), dim3(256), 32768 * sizeof(float), stream>>>(
      entity_pairs, train_edges, user_ids, top_k_ids, entity2edges,
      ent_emb, user_emb, w_ent1, b_ent1, w1, b1, wq, bq, wk, bk, wv, bv,
      w_s, b_s, v1ws, (float*)d_out, bs);
}

// Round 2
// 287.058 us; speedup vs baseline: 2.4737x; 2.4737x over previous
//
#include <hip/hip_runtime.h>
#include <math.h>

#define DEV static __device__ __forceinline__

DEV float rdlane(float v, int l) {
  return __int_as_float(__builtin_amdgcn_readlane(__float_as_int(v), l));
}

DEV float wave_sum64(float v) {
  v += __shfl_xor(v, 32, 64);
  v += __shfl_xor(v, 16, 64);
  v += __shfl_xor(v, 8, 64);
  v += __shfl_xor(v, 4, 64);
  v += __shfl_xor(v, 2, 64);
  v += __shfl_xor(v, 1, 64);
  return v;
}

#define NI 4  // items per wave (weight-read amortization + ILP)

// ---------------------------------------------------------------------------
// Kernel 1: items = bs*33.  j in [0,32): v1[b][j]; j==32: v0_first[b].
// One wave64 per NI items; lane = output feature dim d.
// LDS: rel_emb (64x64) + w_ent0 (128x64) + w0 (192x64) = 96 KB -> 1 block/CU,
// 16 waves/CU, VGPR cap 128 (launch_bounds(1024,4)).
// ---------------------------------------------------------------------------
__global__ __launch_bounds__(1024, 4)
void k_agg_hop(const int* __restrict__ relations, const int* __restrict__ entity_pairs,
               const int* __restrict__ train_edges,
               const int* __restrict__ entity2edges, const int* __restrict__ edge2entities,
               const int* __restrict__ edge2relation,
               const float* __restrict__ ent_emb, const float* __restrict__ rel_emb,
               const float* __restrict__ w_ent0, const float* __restrict__ b_ent0,
               const float* __restrict__ w0, const float* __restrict__ b0,
               float* __restrict__ v1ws, int n_items)
{
  extern __shared__ float Lw[];
  float* Lrel = Lw;            // 4096  (rel_emb: [64][64])
  float* Lwe  = Lw + 4096;     // 8192  (w_ent0: [128][64])
  float* Lw0  = Lw + 12288;    // 12288 (w0:     [192][64])
  for (int t = threadIdx.x; t < 4096; t += blockDim.x) Lrel[t] = rel_emb[t];
  for (int t = threadIdx.x; t < 8192; t += blockDim.x) Lwe[t] = w_ent0[t];
  for (int t = threadIdx.x; t < 12288; t += blockDim.x) Lw0[t] = w0[t];
  __syncthreads();

  const int lane = threadIdx.x & 63;
  const int wid = threadIdx.x >> 6;
  const int gw = blockIdx.x * (blockDim.x >> 6) + wid;
  const int nwaves = gridDim.x * (blockDim.x >> 6);
  const int ngroups = (n_items + NI - 1) / NI;
  const float bent = b_ent0[lane];
  const float b0v = b0[lane];

  for (int g = gw; g < ngroups; g += nwaves) {
    int itm[NI], te[NI], rsel[NI], n0[NI], n1[NI];
#pragma unroll
    for (int q = 0; q < NI; ++q) {
      int item = g * NI + q;
      if (item >= n_items) item = n_items - 1;  // benign duplicate
      itm[q] = item;
      const int b = item / 33;
      const int j = item - b * 33;
      te[q] = train_edges[b];
      if (j < 32) {  // wave-uniform branch
        const int eself = entity2edges[entity_pairs[b * 2 + (j >> 4)] * 16 + (j & 15)];
        rsel[q] = edge2relation[eself];
        n0[q] = edge2entities[eself * 2 + 0];
        n1[q] = edge2entities[eself * 2 + 1];
      } else {
        rsel[q] = relations[b];
        n0[q] = entity_pairs[b * 2 + 0];
        n1[q] = entity_pairs[b * 2 + 1];
      }
    }

    // --- per-lane neighbor-edge gathers (lanes 32..63 duplicate 0..31) ---
    int e[NI];
#pragma unroll
    for (int q = 0; q < NI; ++q) {
      const int myent = ((lane >> 4) & 1) ? n1[q] : n0[q];
      e[q] = entity2edges[myent * 16 + (lane & 15)];
    }
    unsigned long long bal[NI];
    int r[NI];
#pragma unroll
    for (int q = 0; q < NI; ++q) bal[q] = __ballot(e[q] != te[q]);
#pragma unroll
    for (int q = 0; q < NI; ++q) r[q] = edge2relation[e[q]];

    float enA[NI], enB[NI];
#pragma unroll
    for (int q = 0; q < NI; ++q) {
      enA[q] = ent_emb[n0[q] * 64 + lane];
      enB[q] = ent_emb[n1[q] * 64 + lane];
    }

    // --- masked mean of 2x16 neighbor relation vectors (rel_emb in LDS) ---
    float acc0[NI], acc1[NI];
#pragma unroll
    for (int q = 0; q < NI; ++q) { acc0[q] = 0.f; acc1[q] = 0.f; }
#pragma unroll
    for (int s = 0; s < 16; ++s) {
#pragma unroll
      for (int q = 0; q < NI; ++q) {
        const int rA = __builtin_amdgcn_readlane(r[q], s);
        const int rB = __builtin_amdgcn_readlane(r[q], s + 16);
        const float mA = (float)((bal[q] >> s) & 1ull);
        const float mB = (float)((bal[q] >> (s + 16)) & 1ull);
        acc0[q] = fmaf(mA, Lrel[rA * 64 + lane], acc0[q]);
        acc1[q] = fmaf(mB, Lrel[rB * 64 + lane], acc1[q]);
      }
    }
    float selfv[NI];
#pragma unroll
    for (int q = 0; q < NI; ++q) {
      const int c0 = __popcll(bal[q] & 0xFFFFull);
      const int c1 = __popcll(bal[q] & 0xFFFF0000ull);
      acc0[q] *= 1.0f / (float)(c0 ? c0 : 1);
      acc1[q] *= 1.0f / (float)(c1 ? c1 : 1);
      selfv[q] = Lrel[rsel[q] * 64 + lane];
    }

    // --- nv_c = [en_c, mean_c] @ w_ent0 + b_ent0 (weight reads shared) ---
    float nv0[NI], nv1[NI];
#pragma unroll
    for (int q = 0; q < NI; ++q) { nv0[q] = bent; nv1[q] = bent; }
#pragma unroll
    for (int i = 0; i < 64; ++i) {
      const float wA = Lwe[i * 64 + lane];
      const float wB = Lwe[(64 + i) * 64 + lane];
#pragma unroll
      for (int q = 0; q < NI; ++q) {
        nv0[q] = fmaf(rdlane(enA[q], i), wA, nv0[q]);
        nv1[q] = fmaf(rdlane(enB[q], i), wA, nv1[q]);
        nv0[q] = fmaf(rdlane(acc0[q], i), wB, nv0[q]);
        nv1[q] = fmaf(rdlane(acc1[q], i), wB, nv1[q]);
      }
    }

    // --- sv = [self, nv0, nv1] @ w0 + b0 ---
    float sv[NI];
#pragma unroll
    for (int q = 0; q < NI; ++q) sv[q] = b0v;
#pragma unroll
    for (int i = 0; i < 64; ++i) {
      const float w0a = Lw0[i * 64 + lane];
      const float w0b = Lw0[(64 + i) * 64 + lane];
      const float w0c = Lw0[(128 + i) * 64 + lane];
#pragma unroll
      for (int q = 0; q < NI; ++q) {
        sv[q] = fmaf(rdlane(selfv[q], i), w0a, sv[q]);
        sv[q] = fmaf(rdlane(nv0[q], i), w0b, sv[q]);
        sv[q] = fmaf(rdlane(nv1[q], i), w0c, sv[q]);
      }
    }
#pragma unroll
    for (int q = 0; q < NI; ++q) v1ws[itm[q] * 64 + lane] = sv[q];
  }
}

// ---------------------------------------------------------------------------
// Kernel 2: one wave per batch element b (4 waves/block, 1 block/CU).
// Second aggregation -> ctx, then K=10 attention + score.
// LDS: w_ent1 + w1 + wq + wk + wv = 128 KB.
// ---------------------------------------------------------------------------
__global__ __launch_bounds__(256, 2)
void k_ctx_score(const int* __restrict__ entity_pairs, const int* __restrict__ train_edges,
                 const int* __restrict__ user_ids, const int* __restrict__ top_k_ids,
                 const int* __restrict__ entity2edges,
                 const float* __restrict__ ent_emb, const float* __restrict__ user_emb,
                 const float* __restrict__ w_ent1, const float* __restrict__ b_ent1,
                 const float* __restrict__ w1, const float* __restrict__ b1,
                 const float* __restrict__ wq, const float* __restrict__ bq,
                 const float* __restrict__ wk, const float* __restrict__ bk,
                 const float* __restrict__ wv, const float* __restrict__ bv,
                 const float* __restrict__ w_s, const float* __restrict__ b_s,
                 const float* __restrict__ v1ws, float* __restrict__ out, int bs)
{
  extern __shared__ float Lw[];
  float* Lwe = Lw;             // 8192  (w_ent1)
  float* Lw1 = Lw + 8192;      // 12288 (w1)
  float* Lwq = Lw + 20480;     // 4096
  float* Lwk = Lw + 24576;     // 4096
  float* Lwv = Lw + 28672;     // 4096
  for (int t = threadIdx.x; t < 8192; t += blockDim.x) Lwe[t] = w_ent1[t];
  for (int t = threadIdx.x; t < 12288; t += blockDim.x) Lw1[t] = w1[t];
  for (int t = threadIdx.x; t < 4096; t += blockDim.x) {
    Lwq[t] = wq[t]; Lwk[t] = wk[t]; Lwv[t] = wv[t];
  }
  __syncthreads();

  const int lane = threadIdx.x & 63;
  const int wid = threadIdx.x >> 6;
  const int b = blockIdx.x * (blockDim.x >> 6) + wid;
  if (b >= bs) return;

  const int te = train_edges[b];
  const int n0 = entity_pairs[b * 2 + 0];
  const int n1 = entity_pairs[b * 2 + 1];
  const int myent = ((lane >> 4) & 1) ? n1 : n0;
  const int e = entity2edges[myent * 16 + (lane & 15)];
  const unsigned long long bal = __ballot(e != te);
  const int cnt0 = __popcll(bal & 0xFFFFull);
  const int cnt1 = __popcll(bal & 0xFFFF0000ull);

  // issue candidate/user gathers early
  const float u = user_emb[user_ids[b] * 64 + lane];
  float tkv[10];
#pragma unroll
  for (int k = 0; k < 10; ++k) tkv[k] = ent_emb[top_k_ids[b * 10 + k] * 64 + lane];

  const float* vbase = v1ws + (size_t)b * 33 * 64;
  float acc0 = 0.f, acc1 = 0.f;
#pragma unroll
  for (int s = 0; s < 16; ++s) {
    const float mA = (float)((bal >> s) & 1ull);
    const float mB = (float)((bal >> (s + 16)) & 1ull);
    acc0 = fmaf(mA, vbase[s * 64 + lane], acc0);
    acc1 = fmaf(mB, vbase[(16 + s) * 64 + lane], acc1);
  }
  acc0 *= 1.0f / (float)(cnt0 ? cnt0 : 1);
  acc1 *= 1.0f / (float)(cnt1 ? cnt1 : 1);

  const float enA = ent_emb[n0 * 64 + lane];
  const float enB = ent_emb[n1 * 64 + lane];
  float nv0 = b_ent1[lane], nv1 = nv0;
#pragma unroll
  for (int i = 0; i < 64; ++i) {
    const float wA = Lwe[i * 64 + lane];
    const float wB = Lwe[(64 + i) * 64 + lane];
    nv0 = fmaf(rdlane(enA, i), wA, nv0);
    nv1 = fmaf(rdlane(enB, i), wA, nv1);
    nv0 = fmaf(rdlane(acc0, i), wB, nv0);
    nv1 = fmaf(rdlane(acc1, i), wB, nv1);
  }

  const float selfv = vbase[32 * 64 + lane];
  float ctx = b1[lane];
#pragma unroll
  for (int i = 0; i < 64; ++i) {
    ctx = fmaf(rdlane(selfv, i), Lw1[i * 64 + lane], ctx);
    ctx = fmaf(rdlane(nv0, i), Lw1[(64 + i) * 64 + lane], ctx);
    ctx = fmaf(rdlane(nv1, i), Lw1[(128 + i) * 64 + lane], ctx);
  }

  // ---- attention over K=10 candidates (wk/wv reads shared across k) ----
  float q = bq[lane];
#pragma unroll
  for (int i = 0; i < 64; ++i) q = fmaf(rdlane(u, i), Lwq[i * 64 + lane], q);

  float kk[10], vv[10];
  const float bkv = bk[lane], bvv = bv[lane];
#pragma unroll
  for (int k = 0; k < 10; ++k) { kk[k] = bkv; vv[k] = bvv; }
#pragma unroll
  for (int i = 0; i < 64; ++i) {
    const float wkv = Lwk[i * 64 + lane];
    const float wvv = Lwv[i * 64 + lane];
#pragma unroll
    for (int k = 0; k < 10; ++k) {
      const float x = rdlane(tkv[k], i);
      kk[k] = fmaf(x, wkv, kk[k]);
      vv[k] = fmaf(x, wvv, vv[k]);
    }
  }

  float lg[10];
#pragma unroll
  for (int k = 0; k < 10; ++k) lg[k] = wave_sum64(q * kk[k]) * 0.125f;  // 1/sqrt(64)
  float m = lg[0];
#pragma unroll
  for (int k = 1; k < 10; ++k) m = fmaxf(m, lg[k]);
  float den = 0.f;
  float att[10];
#pragma unroll
  for (int k = 0; k < 10; ++k) { att[k] = expf(lg[k] - m); den += att[k]; }
  const float invden = 1.0f / den;
  float uatt = 0.f;
#pragma unroll
  for (int k = 0; k < 10; ++k) uatt = fmaf(att[k] * invden, vv[k], uatt);

  const float sc = wave_sum64(uatt * ctx + ctx * w_s[lane]);
  if (lane == 0) out[b] = sc + b_s[0];
}

extern "C" void kernel_launch(void* const* d_in, const int* in_sizes, int n_in,
                              void* d_out, int out_size, void* d_ws, size_t ws_size,
                              hipStream_t stream) {
  const int* relations     = (const int*)d_in[0];
  const int* entity_pairs  = (const int*)d_in[1];
  const int* train_edges   = (const int*)d_in[2];
  const int* user_ids      = (const int*)d_in[3];
  const int* top_k_ids     = (const int*)d_in[4];
  const int* entity2edges  = (const int*)d_in[5];
  const int* edge2entities = (const int*)d_in[6];
  const int* edge2relation = (const int*)d_in[7];
  const float* ent_emb  = (const float*)d_in[8];
  const float* rel_emb  = (const float*)d_in[9];
  const float* user_emb = (const float*)d_in[10];
  const float* w_ent0 = (const float*)d_in[11];
  const float* b_ent0 = (const float*)d_in[12];
  const float* w0     = (const float*)d_in[13];
  const float* b0     = (const float*)d_in[14];
  const float* w_ent1 = (const float*)d_in[15];
  const float* b_ent1 = (const float*)d_in[16];
  const float* w1     = (const float*)d_in[17];
  const float* b1     = (const float*)d_in[18];
  const float* wq  = (const float*)d_in[19];
  const float* bq  = (const float*)d_in[20];
  const float* wk  = (const float*)d_in[21];
  const float* bk  = (const float*)d_in[22];
  const float* wv  = (const float*)d_in[23];
  const float* bv  = (const float*)d_in[24];
  const float* w_s = (const float*)d_in[25];
  const float* b_s = (const float*)d_in[26];

  const int bs = in_sizes[0];
  const int n_items = bs * 33;
  float* v1ws = (float*)d_ws;  // n_items * 64 floats (~8.3 MB)

  k_agg_hop<<<dim3(256), dim3(1024), 24576 * sizeof(float), stream>>>(
      relations, entity_pairs, train_edges, entity2edges, edge2entities,
      edge2relation, ent_emb, rel_emb, w_ent0, b_ent0, w0, b0, v1ws, n_items);

  k_ctx_score<<<dim3((bs + 3) / 4), dim3(256), 32768 * sizeof(float), stream>>>(
      entity_pairs, train_edges, user_ids, top_k_ids, entity2edges,
      ent_emb, user_emb, w_ent1, b_ent1, w1, b1, wq, bq, wk, bk, wv, bv,
      w_s, b_s, v1ws, (float*)d_out, bs);
}

// Round 3
// 119.336 us; speedup vs baseline: 5.9505x; 2.4055x over previous
//
#include <hip/hip_runtime.h>
#include <math.h>

#define DEV static __device__ __forceinline__

DEV float rdlane(float v, int l) {
  return __int_as_float(__builtin_amdgcn_readlane(__float_as_int(v), l));
}

DEV float wave_sum64(float v) {
  v += __shfl_xor(v, 32, 64);
  v += __shfl_xor(v, 16, 64);
  v += __shfl_xor(v, 8, 64);
  v += __shfl_xor(v, 4, 64);
  v += __shfl_xor(v, 2, 64);
  v += __shfl_xor(v, 1, 64);
  return v;
}

// ---------------------------------------------------------------------------
// Kernel 1: items = bs*33.  j in [0,32): v1[b][j]; j==32: v0_first[b].
// One wave64 per 4 items; lane = output feature dim d.
// All x-operands broadcast via wave-uniform LDS/global reads (no readlane).
// Weights transposed in LDS ([d][i], stride ≡ 4 mod 32) for b128 reads.
// LDS floats: Lrel[65][64]=4160 | LweT[64][132]=8448 | Lw0T[64][196]=12544 |
//             Xstage 16 waves x 512  => 33344 floats = 130.25 KB, 1 block/CU.
// ---------------------------------------------------------------------------
__global__ __launch_bounds__(1024, 4)
void k_agg_hop(const int* __restrict__ relations, const int* __restrict__ entity_pairs,
               const int* __restrict__ train_edges,
               const int* __restrict__ entity2edges, const int* __restrict__ edge2entities,
               const int* __restrict__ edge2relation,
               const float* __restrict__ ent_emb, const float* __restrict__ rel_emb,
               const float* __restrict__ w_ent0, const float* __restrict__ b_ent0,
               const float* __restrict__ w0, const float* __restrict__ b0,
               float* __restrict__ v1ws, int n_items)
{
  extern __shared__ float Lw[];
  float* Lrel = Lw;            // [65][64], row 64 = zeros
  float* LweT = Lw + 4160;     // [64][132]  LweT[d*132+i] = w_ent0[i][d]
  float* Lw0T = Lw + 12608;    // [64][196]  Lw0T[d*196+i] = w0[i][d]
  float* Xall = Lw + 25152;    // per-wave 512-float staging

  for (int t = threadIdx.x; t < 4096; t += blockDim.x) Lrel[t] = rel_emb[t];
  if (threadIdx.x < 64) Lrel[4096 + threadIdx.x] = 0.f;
  for (int t = threadIdx.x; t < 8192; t += blockDim.x) {
    const int i = t >> 6, d = t & 63;
    LweT[d * 132 + i] = w_ent0[t];
  }
  for (int t = threadIdx.x; t < 12288; t += blockDim.x) {
    const int i = t >> 6, d = t & 63;
    Lw0T[d * 196 + i] = w0[t];
  }
  __syncthreads();

  const int lane = threadIdx.x & 63;
  const int wid = threadIdx.x >> 6;
  float* Xw = Xall + wid * 512;
  int* Xi = (int*)Xw;

  const int gw = blockIdx.x * 16 + wid;
  const int nwaves = gridDim.x * 16;
  const int ngroups = (n_items + 3) >> 2;
  const int gpw = (ngroups + nwaves - 1) / nwaves;   // groups per wave (==3 here)
  const float bent = b_ent0[lane];
  const float b0v = b0[lane];
  const float* wrow = &LweT[lane * 132];
  const float* w0row = &Lw0T[lane * 196];

  for (int gg = 0; gg < gpw; ++gg) {
    const int g = gw * gpw + gg;
    if (g >= ngroups) break;

    int te[4], rsel[4], n0s[4], n1s[4], itm[4];
#pragma unroll
    for (int q = 0; q < 4; ++q) {
      int item = g * 4 + q;
      if (item >= n_items) item = n_items - 1;  // benign duplicate
      itm[q] = item;
      const int b = item / 33;
      const int j = item - b * 33;
      te[q] = __builtin_amdgcn_readfirstlane(train_edges[b]);
      int n0, n1, rs;
      if (j < 32) {  // wave-uniform branch
        const int eself = entity2edges[entity_pairs[b * 2 + (j >> 4)] * 16 + (j & 15)];
        rs = edge2relation[eself];
        n0 = edge2entities[eself * 2 + 0];
        n1 = edge2entities[eself * 2 + 1];
      } else {
        rs = relations[b];
        n0 = entity_pairs[b * 2 + 0];
        n1 = entity_pairs[b * 2 + 1];
      }
      rsel[q] = __builtin_amdgcn_readfirstlane(rs);
      n0s[q] = __builtin_amdgcn_readfirstlane(n0);
      n1s[q] = __builtin_amdgcn_readfirstlane(n1);
    }

    // --- per-lane neighbor gathers; stage masked rel-row indices as ints ---
    unsigned long long bal[4];
#pragma unroll
    for (int q = 0; q < 4; ++q) {
      const int myent = ((lane >> 4) & 1) ? n1s[q] : n0s[q];
      const int e = entity2edges[myent * 16 + (lane & 15)];
      const bool keep = (e != te[q]);
      bal[q] = __ballot(keep);
      const int r = edge2relation[e];
      Xi[q * 128 + lane] = keep ? r : 64;  // row 64 of Lrel is zeros
    }

    // --- masked mean: uniform int4 index reads + row ADDs from Lrel ---
    float acc0[4], acc1[4];
#pragma unroll
    for (int q = 0; q < 4; ++q) {
      float a0 = 0.f, a1 = 0.f;
#pragma unroll
      for (int sb = 0; sb < 4; ++sb) {
        const int4 r0 = *(const int4*)&Xi[q * 128 + 4 * sb];
        const int4 r1 = *(const int4*)&Xi[q * 128 + 16 + 4 * sb];
        a0 += Lrel[r0.x * 64 + lane]; a0 += Lrel[r0.y * 64 + lane];
        a0 += Lrel[r0.z * 64 + lane]; a0 += Lrel[r0.w * 64 + lane];
        a1 += Lrel[r1.x * 64 + lane]; a1 += Lrel[r1.y * 64 + lane];
        a1 += Lrel[r1.z * 64 + lane]; a1 += Lrel[r1.w * 64 + lane];
      }
      const int c0 = __popcll(bal[q] & 0xFFFFull);
      const int c1 = __popcll(bal[q] & 0xFFFF0000ull);
      acc0[q] = a0 / (float)(c0 ? c0 : 1);
      acc1[q] = a1 / (float)(c1 ? c1 : 1);
    }

    // --- stage acc vectors (lane = d) for uniform reads ---
#pragma unroll
    for (int q = 0; q < 4; ++q) {
      Xw[q * 128 + lane] = acc0[q];
      Xw[q * 128 + 64 + lane] = acc1[q];
    }

    // --- stage 1: nv_c = [en_c | acc_c] @ w_ent0 + b_ent0 ---
    float nv0[4], nv1[4];
#pragma unroll
    for (int q = 0; q < 4; ++q) { nv0[q] = bent; nv1[q] = bent; }
#pragma unroll
    for (int ib = 0; ib < 16; ++ib) {
      const float4 wE = *(const float4*)&wrow[4 * ib];
      const float4 wA = *(const float4*)&wrow[64 + 4 * ib];
#pragma unroll
      for (int q = 0; q < 4; ++q) {
        const float4 xa = *(const float4*)(ent_emb + (size_t)n0s[q] * 64 + 4 * ib);
        const float4 xb = *(const float4*)(ent_emb + (size_t)n1s[q] * 64 + 4 * ib);
        const float4 aa = *(const float4*)&Xw[q * 128 + 4 * ib];
        const float4 ab = *(const float4*)&Xw[q * 128 + 64 + 4 * ib];
        nv0[q] = fmaf(xa.x, wE.x, nv0[q]); nv0[q] = fmaf(xa.y, wE.y, nv0[q]);
        nv0[q] = fmaf(xa.z, wE.z, nv0[q]); nv0[q] = fmaf(xa.w, wE.w, nv0[q]);
        nv0[q] = fmaf(aa.x, wA.x, nv0[q]); nv0[q] = fmaf(aa.y, wA.y, nv0[q]);
        nv0[q] = fmaf(aa.z, wA.z, nv0[q]); nv0[q] = fmaf(aa.w, wA.w, nv0[q]);
        nv1[q] = fmaf(xb.x, wE.x, nv1[q]); nv1[q] = fmaf(xb.y, wE.y, nv1[q]);
        nv1[q] = fmaf(xb.z, wE.z, nv1[q]); nv1[q] = fmaf(xb.w, wE.w, nv1[q]);
        nv1[q] = fmaf(ab.x, wA.x, nv1[q]); nv1[q] = fmaf(ab.y, wA.y, nv1[q]);
        nv1[q] = fmaf(ab.z, wA.z, nv1[q]); nv1[q] = fmaf(ab.w, wA.w, nv1[q]);
      }
    }

    // --- stage nv vectors (reuse same slots; in-wave DS ordering) ---
#pragma unroll
    for (int q = 0; q < 4; ++q) {
      Xw[q * 128 + lane] = nv0[q];
      Xw[q * 128 + 64 + lane] = nv1[q];
    }

    // --- stage 2: sv = [self | nv0 | nv1] @ w0 + b0 (self read from Lrel) ---
    float sv[4];
#pragma unroll
    for (int q = 0; q < 4; ++q) sv[q] = b0v;
#pragma unroll
    for (int ib = 0; ib < 16; ++ib) {
      const float4 wS = *(const float4*)&w0row[4 * ib];
      const float4 wN0 = *(const float4*)&w0row[64 + 4 * ib];
      const float4 wN1 = *(const float4*)&w0row[128 + 4 * ib];
#pragma unroll
      for (int q = 0; q < 4; ++q) {
        const float4 xs = *(const float4*)&Lrel[rsel[q] * 64 + 4 * ib];
        const float4 x0 = *(const float4*)&Xw[q * 128 + 4 * ib];
        const float4 x1 = *(const float4*)&Xw[q * 128 + 64 + 4 * ib];
        sv[q] = fmaf(xs.x, wS.x, sv[q]); sv[q] = fmaf(xs.y, wS.y, sv[q]);
        sv[q] = fmaf(xs.z, wS.z, sv[q]); sv[q] = fmaf(xs.w, wS.w, sv[q]);
        sv[q] = fmaf(x0.x, wN0.x, sv[q]); sv[q] = fmaf(x0.y, wN0.y, sv[q]);
        sv[q] = fmaf(x0.z, wN0.z, sv[q]); sv[q] = fmaf(x0.w, wN0.w, sv[q]);
        sv[q] = fmaf(x1.x, wN1.x, sv[q]); sv[q] = fmaf(x1.y, wN1.y, sv[q]);
        sv[q] = fmaf(x1.z, wN1.z, sv[q]); sv[q] = fmaf(x1.w, wN1.w, sv[q]);
      }
    }
#pragma unroll
    for (int q = 0; q < 4; ++q) v1ws[itm[q] * 64 + lane] = sv[q];
  }
}

// ---------------------------------------------------------------------------
// Kernel 2: unchanged from R1 (one wave per batch element).
// ---------------------------------------------------------------------------
__global__ __launch_bounds__(256, 2)
void k_ctx_score(const int* __restrict__ entity_pairs, const int* __restrict__ train_edges,
                 const int* __restrict__ user_ids, const int* __restrict__ top_k_ids,
                 const int* __restrict__ entity2edges,
                 const float* __restrict__ ent_emb, const float* __restrict__ user_emb,
                 const float* __restrict__ w_ent1, const float* __restrict__ b_ent1,
                 const float* __restrict__ w1, const float* __restrict__ b1,
                 const float* __restrict__ wq, const float* __restrict__ bq,
                 const float* __restrict__ wk, const float* __restrict__ bk,
                 const float* __restrict__ wv, const float* __restrict__ bv,
                 const float* __restrict__ w_s, const float* __restrict__ b_s,
                 const float* __restrict__ v1ws, float* __restrict__ out, int bs)
{
  extern __shared__ float Lw[];
  float* Lwe = Lw;             // 8192  (w_ent1)
  float* Lw1 = Lw + 8192;      // 12288 (w1)
  float* Lwq = Lw + 20480;     // 4096
  float* Lwk = Lw + 24576;     // 4096
  float* Lwv = Lw + 28672;     // 4096
  for (int t = threadIdx.x; t < 8192; t += blockDim.x) Lwe[t] = w_ent1[t];
  for (int t = threadIdx.x; t < 12288; t += blockDim.x) Lw1[t] = w1[t];
  for (int t = threadIdx.x; t < 4096; t += blockDim.x) {
    Lwq[t] = wq[t]; Lwk[t] = wk[t]; Lwv[t] = wv[t];
  }
  __syncthreads();

  const int lane = threadIdx.x & 63;
  const int wid = threadIdx.x >> 6;
  const int b = blockIdx.x * (blockDim.x >> 6) + wid;
  if (b >= bs) return;

  const int te = train_edges[b];
  const int n0 = entity_pairs[b * 2 + 0];
  const int n1 = entity_pairs[b * 2 + 1];
  const int myent = ((lane >> 4) & 1) ? n1 : n0;
  const int e = entity2edges[myent * 16 + (lane & 15)];
  const unsigned long long bal = __ballot(e != te);
  const int cnt0 = __popcll(bal & 0xFFFFull);
  const int cnt1 = __popcll(bal & 0xFFFF0000ull);

  const float u = user_emb[user_ids[b] * 64 + lane];
  float tkv[10];
#pragma unroll
  for (int k = 0; k < 10; ++k) tkv[k] = ent_emb[top_k_ids[b * 10 + k] * 64 + lane];

  const float* vbase = v1ws + (size_t)b * 33 * 64;
  float acc0 = 0.f, acc1 = 0.f;
#pragma unroll
  for (int s = 0; s < 16; ++s) {
    const float mA = (float)((bal >> s) & 1ull);
    const float mB = (float)((bal >> (s + 16)) & 1ull);
    acc0 = fmaf(mA, vbase[s * 64 + lane], acc0);
    acc1 = fmaf(mB, vbase[(16 + s) * 64 + lane], acc1);
  }
  acc0 *= 1.0f / (float)(cnt0 ? cnt0 : 1);
  acc1 *= 1.0f / (float)(cnt1 ? cnt1 : 1);

  const float enA = ent_emb[n0 * 64 + lane];
  const float enB = ent_emb[n1 * 64 + lane];
  float nv0 = b_ent1[lane], nv1 = nv0;
#pragma unroll
  for (int i = 0; i < 64; ++i) {
    const float wA = Lwe[i * 64 + lane];
    const float wB = Lwe[(64 + i) * 64 + lane];
    nv0 = fmaf(rdlane(enA, i), wA, nv0);
    nv1 = fmaf(rdlane(enB, i), wA, nv1);
    nv0 = fmaf(rdlane(acc0, i), wB, nv0);
    nv1 = fmaf(rdlane(acc1, i), wB, nv1);
  }

  const float selfv = vbase[32 * 64 + lane];
  float ctx = b1[lane];
#pragma unroll
  for (int i = 0; i < 64; ++i) {
    ctx = fmaf(rdlane(selfv, i), Lw1[i * 64 + lane], ctx);
    ctx = fmaf(rdlane(nv0, i), Lw1[(64 + i) * 64 + lane], ctx);
    ctx = fmaf(rdlane(nv1, i), Lw1[(128 + i) * 64 + lane], ctx);
  }

  float q = bq[lane];
#pragma unroll
  for (int i = 0; i < 64; ++i) q = fmaf(rdlane(u, i), Lwq[i * 64 + lane], q);

  float kk[10], vv[10];
  const float bkv = bk[lane], bvv = bv[lane];
#pragma unroll
  for (int k = 0; k < 10; ++k) { kk[k] = bkv; vv[k] = bvv; }
#pragma unroll
  for (int i = 0; i < 64; ++i) {
    const float wkv = Lwk[i * 64 + lane];
    const float wvv = Lwv[i * 64 + lane];
#pragma unroll
    for (int k = 0; k < 10; ++k) {
      const float x = rdlane(tkv[k], i);
      kk[k] = fmaf(x, wkv, kk[k]);
      vv[k] = fmaf(x, wvv, vv[k]);
    }
  }

  float lg[10];
#pragma unroll
  for (int k = 0; k < 10; ++k) lg[k] = wave_sum64(q * kk[k]) * 0.125f;
  float m = lg[0];
#pragma unroll
  for (int k = 1; k < 10; ++k) m = fmaxf(m, lg[k]);
  float den = 0.f;
  float att[10];
#pragma unroll
  for (int k = 0; k < 10; ++k) { att[k] = expf(lg[k] - m); den += att[k]; }
  const float invden = 1.0f / den;
  float uatt = 0.f;
#pragma unroll
  for (int k = 0; k < 10; ++k) uatt = fmaf(att[k] * invden, vv[k], uatt);

  const float sc = wave_sum64(uatt * ctx + ctx * w_s[lane]);
  if (lane == 0) out[b] = sc + b_s[0];
}

extern "C" void kernel_launch(void* const* d_in, const int* in_sizes, int n_in,
                              void* d_out, int out_size, void* d_ws, size_t ws_size,
                              hipStream_t stream) {
  const int* relations     = (const int*)d_in[0];
  const int* entity_pairs  = (const int*)d_in[1];
  const int* train_edges   = (const int*)d_in[2];
  const int* user_ids      = (const int*)d_in[3];
  const int* top_k_ids     = (const int*)d_in[4];
  const int* entity2edges  = (const int*)d_in[5];
  const int* edge2entities = (const int*)d_in[6];
  const int* edge2relation = (const int*)d_in[7];
  const float* ent_emb  = (const float*)d_in[8];
  const float* rel_emb  = (const float*)d_in[9];
  const float* user_emb = (const float*)d_in[10];
  const float* w_ent0 = (const float*)d_in[11];
  const float* b_ent0 = (const float*)d_in[12];
  const float* w0     = (const float*)d_in[13];
  const float* b0     = (const float*)d_in[14];
  const float* w_ent1 = (const float*)d_in[15];
  const float* b_ent1 = (const float*)d_in[16];
  const float* w1     = (const float*)d_in[17];
  const float* b1     = (const float*)d_in[18];
  const float* wq  = (const float*)d_in[19];
  const float* bq  = (const float*)d_in[20];
  const float* wk  = (const float*)d_in[21];
  const float* bk  = (const float*)d_in[22];
  const float* wv  = (const float*)d_in[23];
  const float* bv  = (const float*)d_in[24];
  const float* w_s = (const float*)d_in[25];
  const float* b_s = (const float*)d_in[26];

  const int bs = in_sizes[0];
  const int n_items = bs * 33;
  float* v1ws = (float*)d_ws;  // n_items * 64 floats (~8.3 MB)

  // 33792 items -> 8448 groups = 176 blocks x 16 waves x exactly 3 groups.
  k_agg_hop<<<dim3(176), dim3(1024), 33344 * sizeof(float), stream>>>(
      relations, entity_pairs, train_edges, entity2edges, edge2entities,
      edge2relation, ent_emb, rel_emb, w_ent0, b_ent0, w0, b0, v1ws, n_items);

  k_ctx_score<<<dim3((bs + 3) / 4), dim3(256), 32768 * sizeof(float), stream>>>(
      entity_pairs, train_edges, user_ids, top_k_ids, entity2edges,
      ent_emb, user_emb, w_ent1, b_ent1, w1, b1, wq, bq, wk, bk, wv, bv,
      w_s, b_s, v1ws, (float*)d_out, bs);
}

// Round 4
// 115.597 us; speedup vs baseline: 6.1430x; 1.0323x over previous
//
#include <hip/hip_runtime.h>
#include <math.h>

#define DEV static __device__ __forceinline__

DEV float rdlane(float v, int l) {
  return __int_as_float(__builtin_amdgcn_readlane(__float_as_int(v), l));
}

DEV float wave_sum64(float v) {
  v += __shfl_xor(v, 32, 64);
  v += __shfl_xor(v, 16, 64);
  v += __shfl_xor(v, 8, 64);
  v += __shfl_xor(v, 4, 64);
  v += __shfl_xor(v, 2, 64);
  v += __shfl_xor(v, 1, 64);
  return v;
}

// ---------------------------------------------------------------------------
// Kernel 1: items = bs*33.  j in [0,32): v1[b][j]; j==32: v0_first[b].
// One wave64 per 4 items; lane = output feature dim d.
// Pipe split: weights = LDS b128 (transposed, amortized over 4 items);
// scalar-indexed rows (ent/rel) = SMEM (uniform float4 loads);
// wave-resident vectors (acc, nv) = readlane broadcast (private SIMD).
// LDS: Lrel[65][64] + LweT[64][132] + Lw0T[64][196] = 25152 floats = 98.25 KB.
// Grid: 256 blocks x 16 waves; 8448 groups = 2/wave + 1 extra on wave0/block.
// ---------------------------------------------------------------------------
__global__ __launch_bounds__(1024, 4)
void k_agg_hop(const int* __restrict__ relations, const int* __restrict__ entity_pairs,
               const int* __restrict__ train_edges,
               const int* __restrict__ entity2edges, const int* __restrict__ edge2entities,
               const int* __restrict__ edge2relation,
               const float* __restrict__ ent_emb, const float* __restrict__ rel_emb,
               const float* __restrict__ w_ent0, const float* __restrict__ b_ent0,
               const float* __restrict__ w0, const float* __restrict__ b0,
               float* __restrict__ v1ws, int n_items)
{
  extern __shared__ float Lw[];
  float* Lrel = Lw;            // [65][64], row 64 = zeros
  float* LweT = Lw + 4160;     // [64][132]  LweT[d*132+i] = w_ent0[i][d]
  float* Lw0T = Lw + 12608;    // [64][196]  Lw0T[d*196+i] = w0[i][d]

  for (int t = threadIdx.x; t < 4096; t += blockDim.x) Lrel[t] = rel_emb[t];
  if (threadIdx.x < 64) Lrel[4096 + threadIdx.x] = 0.f;
  for (int t = threadIdx.x; t < 8192; t += blockDim.x)
    LweT[(t & 63) * 132 + (t >> 6)] = w_ent0[t];
  for (int t = threadIdx.x; t < 12288; t += blockDim.x)
    Lw0T[(t & 63) * 196 + (t >> 6)] = w0[t];
  __syncthreads();

  const int lane = threadIdx.x & 63;
  const int wid = threadIdx.x >> 6;
  const int gw = blockIdx.x * 16 + wid;
  const int nwaves = gridDim.x * 16;
  const int ngroups = (n_items + 3) >> 2;
  const int base = ngroups / nwaves;           // ==2 for bs=1024
  const float bent = b_ent0[lane];
  const float b0v = b0[lane];
  const float* wrow = &LweT[lane * 132];
  const float* w0row = &Lw0T[lane * 196];

  for (int slot = 0; ; ++slot) {
    int g;
    if (slot < base) {
      g = gw * base + slot;
    } else {                                   // leftover groups: one per block on wave 0
      if (wid != 0) break;
      g = base * nwaves + blockIdx.x + (slot - base) * gridDim.x;
      if (g >= ngroups) break;
    }
    if (g >= ngroups) break;

    int te[4], rsel[4], n0s[4], n1s[4], itm[4];
#pragma unroll
    for (int q = 0; q < 4; ++q) {
      int item = g * 4 + q;
      if (item >= n_items) item = n_items - 1;  // benign duplicate
      itm[q] = item;
      const int b = item / 33;
      const int j = item - b * 33;
      te[q] = __builtin_amdgcn_readfirstlane(train_edges[b]);
      int n0, n1, rs;
      if (j < 32) {  // wave-uniform branch
        const int eself = entity2edges[entity_pairs[b * 2 + (j >> 4)] * 16 + (j & 15)];
        rs = edge2relation[eself];
        n0 = edge2entities[eself * 2 + 0];
        n1 = edge2entities[eself * 2 + 1];
      } else {
        rs = relations[b];
        n0 = entity_pairs[b * 2 + 0];
        n1 = entity_pairs[b * 2 + 1];
      }
      rsel[q] = __builtin_amdgcn_readfirstlane(rs);
      n0s[q] = __builtin_amdgcn_readfirstlane(n0);
      n1s[q] = __builtin_amdgcn_readfirstlane(n1);
    }

    // --- masked mean: per-lane gather of rel index, rl-broadcast row reads ---
    float acc0[4], acc1[4];
#pragma unroll
    for (int q = 0; q < 4; ++q) {
      const int myent = ((lane >> 4) & 1) ? n1s[q] : n0s[q];
      const int e = entity2edges[myent * 16 + (lane & 15)];
      const bool keep = (e != te[q]);
      const unsigned long long bal = __ballot(keep);
      const int r = keep ? edge2relation[e] : 64;  // row 64 of Lrel is zeros
      float a0 = 0.f, a1 = 0.f;
#pragma unroll
      for (int s = 0; s < 16; ++s) {
        const int rA = __builtin_amdgcn_readlane(r, s);
        const int rB = __builtin_amdgcn_readlane(r, s + 16);
        a0 += Lrel[rA * 64 + lane];
        a1 += Lrel[rB * 64 + lane];
      }
      const int c0 = __popcll(bal & 0xFFFFull);
      const int c1 = __popcll(bal & 0xFFFF0000ull);
      acc0[q] = a0 / (float)(c0 ? c0 : 1);
      acc1[q] = a1 / (float)(c1 ? c1 : 1);
    }

    // --- stage 1: nv_c = [en_c | acc_c] @ w_ent0 + b_ent0 ---
    // en rows: uniform (SMEM) float4; acc: readlane broadcast.
    float nv0[4], nv1[4];
#pragma unroll
    for (int q = 0; q < 4; ++q) { nv0[q] = bent; nv1[q] = bent; }
#pragma unroll
    for (int ib = 0; ib < 16; ++ib) {
      const float4 wE = *(const float4*)&wrow[4 * ib];
      const float4 wA = *(const float4*)&wrow[64 + 4 * ib];
#pragma unroll
      for (int q = 0; q < 4; ++q) {
        const float4 xa = *(const float4*)(ent_emb + (size_t)n0s[q] * 64 + 4 * ib);
        const float4 xb = *(const float4*)(ent_emb + (size_t)n1s[q] * 64 + 4 * ib);
        nv0[q] = fmaf(xa.x, wE.x, nv0[q]); nv0[q] = fmaf(xa.y, wE.y, nv0[q]);
        nv0[q] = fmaf(xa.z, wE.z, nv0[q]); nv0[q] = fmaf(xa.w, wE.w, nv0[q]);
        nv1[q] = fmaf(xb.x, wE.x, nv1[q]); nv1[q] = fmaf(xb.y, wE.y, nv1[q]);
        nv1[q] = fmaf(xb.z, wE.z, nv1[q]); nv1[q] = fmaf(xb.w, wE.w, nv1[q]);
        nv0[q] = fmaf(rdlane(acc0[q], 4 * ib + 0), wA.x, nv0[q]);
        nv0[q] = fmaf(rdlane(acc0[q], 4 * ib + 1), wA.y, nv0[q]);
        nv0[q] = fmaf(rdlane(acc0[q], 4 * ib + 2), wA.z, nv0[q]);
        nv0[q] = fmaf(rdlane(acc0[q], 4 * ib + 3), wA.w, nv0[q]);
        nv1[q] = fmaf(rdlane(acc1[q], 4 * ib + 0), wA.x, nv1[q]);
        nv1[q] = fmaf(rdlane(acc1[q], 4 * ib + 1), wA.y, nv1[q]);
        nv1[q] = fmaf(rdlane(acc1[q], 4 * ib + 2), wA.z, nv1[q]);
        nv1[q] = fmaf(rdlane(acc1[q], 4 * ib + 3), wA.w, nv1[q]);
      }
    }

    // --- stage 2: sv = [self | nv0 | nv1] @ w0 + b0 ---
    // self rows: uniform rel_emb (SMEM); nv: readlane broadcast.
    float sv[4];
#pragma unroll
    for (int q = 0; q < 4; ++q) sv[q] = b0v;
#pragma unroll
    for (int ib = 0; ib < 16; ++ib) {
      const float4 wS = *(const float4*)&w0row[4 * ib];
      const float4 wN0 = *(const float4*)&w0row[64 + 4 * ib];
      const float4 wN1 = *(const float4*)&w0row[128 + 4 * ib];
#pragma unroll
      for (int q = 0; q < 4; ++q) {
        const float4 xs = *(const float4*)(rel_emb + (size_t)rsel[q] * 64 + 4 * ib);
        sv[q] = fmaf(xs.x, wS.x, sv[q]); sv[q] = fmaf(xs.y, wS.y, sv[q]);
        sv[q] = fmaf(xs.z, wS.z, sv[q]); sv[q] = fmaf(xs.w, wS.w, sv[q]);
        sv[q] = fmaf(rdlane(nv0[q], 4 * ib + 0), wN0.x, sv[q]);
        sv[q] = fmaf(rdlane(nv0[q], 4 * ib + 1), wN0.y, sv[q]);
        sv[q] = fmaf(rdlane(nv0[q], 4 * ib + 2), wN0.z, sv[q]);
        sv[q] = fmaf(rdlane(nv0[q], 4 * ib + 3), wN0.w, sv[q]);
        sv[q] = fmaf(rdlane(nv1[q], 4 * ib + 0), wN1.x, sv[q]);
        sv[q] = fmaf(rdlane(nv1[q], 4 * ib + 1), wN1.y, sv[q]);
        sv[q] = fmaf(rdlane(nv1[q], 4 * ib + 2), wN1.z, sv[q]);
        sv[q] = fmaf(rdlane(nv1[q], 4 * ib + 3), wN1.w, sv[q]);
      }
    }
#pragma unroll
    for (int q = 0; q < 4; ++q) v1ws[itm[q] * 64 + lane] = sv[q];
  }
}

// ---------------------------------------------------------------------------
// Kernel 2: 128 blocks x 16 waves... -> 128 blocks x 1024 thr, 1 b per wave.
// All scalar-indexed rows (v1 self, tk, user) via SMEM; acc/nv via readlane;
// weights transposed in LDS; wk/wv b128 reads shared across all 10 candidates.
// LDS: LweT1[64][132] + Lw1T[64][196] + L{q,k,v}T[64][68] = 34048 fl = 133 KB.
// ---------------------------------------------------------------------------
__global__ __launch_bounds__(1024, 4)
void k_ctx_score(const int* __restrict__ entity_pairs, const int* __restrict__ train_edges,
                 const int* __restrict__ user_ids, const int* __restrict__ top_k_ids,
                 const int* __restrict__ entity2edges,
                 const float* __restrict__ ent_emb, const float* __restrict__ user_emb,
                 const float* __restrict__ w_ent1, const float* __restrict__ b_ent1,
                 const float* __restrict__ w1, const float* __restrict__ b1,
                 const float* __restrict__ wq, const float* __restrict__ bq,
                 const float* __restrict__ wk, const float* __restrict__ bk,
                 const float* __restrict__ wv, const float* __restrict__ bv,
                 const float* __restrict__ w_s, const float* __restrict__ b_s,
                 const float* __restrict__ v1ws, float* __restrict__ out, int bs)
{
  extern __shared__ float Lw[];
  float* LweT = Lw;            // [64][132]
  float* Lw1T = Lw + 8448;     // [64][196]
  float* LqT  = Lw + 20992;    // [64][68]
  float* LkT  = Lw + 25344;    // [64][68]
  float* LvT  = Lw + 29696;    // [64][68]
  for (int t = threadIdx.x; t < 8192; t += blockDim.x)
    LweT[(t & 63) * 132 + (t >> 6)] = w_ent1[t];
  for (int t = threadIdx.x; t < 12288; t += blockDim.x)
    Lw1T[(t & 63) * 196 + (t >> 6)] = w1[t];
  for (int t = threadIdx.x; t < 4096; t += blockDim.x) {
    const int d = t & 63, i = t >> 6;
    LqT[d * 68 + i] = wq[t];
    LkT[d * 68 + i] = wk[t];
    LvT[d * 68 + i] = wv[t];
  }
  __syncthreads();

  const int lane = threadIdx.x & 63;
  const int wid = threadIdx.x >> 6;
  const int b = blockIdx.x * 16 + wid;
  if (b >= bs) return;

  const int te = __builtin_amdgcn_readfirstlane(train_edges[b]);
  const int n0 = __builtin_amdgcn_readfirstlane(entity_pairs[b * 2 + 0]);
  const int n1 = __builtin_amdgcn_readfirstlane(entity_pairs[b * 2 + 1]);
  const int uid = __builtin_amdgcn_readfirstlane(user_ids[b]);
  int tkid[10];
#pragma unroll
  for (int k = 0; k < 10; ++k)
    tkid[k] = __builtin_amdgcn_readfirstlane(top_k_ids[b * 10 + k]);

  const int myent = ((lane >> 4) & 1) ? n1 : n0;
  const int e = entity2edges[myent * 16 + (lane & 15)];
  const unsigned long long bal = __ballot(e != te);
  const int cnt0 = __popcll(bal & 0xFFFFull);
  const int cnt1 = __popcll(bal & 0xFFFF0000ull);

  // masked mean over v1 (rows consecutive; per-lane coalesced loads)
  const float* vbase = v1ws + (size_t)b * 33 * 64;
  float acc0 = 0.f, acc1 = 0.f;
#pragma unroll
  for (int s = 0; s < 16; ++s) {
    const float mA = (float)((bal >> s) & 1ull);
    const float mB = (float)((bal >> (s + 16)) & 1ull);
    acc0 = fmaf(mA, vbase[s * 64 + lane], acc0);
    acc1 = fmaf(mB, vbase[(16 + s) * 64 + lane], acc1);
  }
  acc0 *= 1.0f / (float)(cnt0 ? cnt0 : 1);
  acc1 *= 1.0f / (float)(cnt1 ? cnt1 : 1);

  // --- nv = [en | acc] @ w_ent1 + b_ent1 ---
  float nv0 = b_ent1[lane], nv1 = nv0;
  const float* wrow = &LweT[lane * 132];
#pragma unroll
  for (int ib = 0; ib < 16; ++ib) {
    const float4 wE = *(const float4*)&wrow[4 * ib];
    const float4 wA = *(const float4*)&wrow[64 + 4 * ib];
    const float4 xa = *(const float4*)(ent_emb + (size_t)n0 * 64 + 4 * ib);
    const float4 xb = *(const float4*)(ent_emb + (size_t)n1 * 64 + 4 * ib);
    nv0 = fmaf(xa.x, wE.x, nv0); nv0 = fmaf(xa.y, wE.y, nv0);
    nv0 = fmaf(xa.z, wE.z, nv0); nv0 = fmaf(xa.w, wE.w, nv0);
    nv1 = fmaf(xb.x, wE.x, nv1); nv1 = fmaf(xb.y, wE.y, nv1);
    nv1 = fmaf(xb.z, wE.z, nv1); nv1 = fmaf(xb.w, wE.w, nv1);
    nv0 = fmaf(rdlane(acc0, 4 * ib + 0), wA.x, nv0);
    nv0 = fmaf(rdlane(acc0, 4 * ib + 1), wA.y, nv0);
    nv0 = fmaf(rdlane(acc0, 4 * ib + 2), wA.z, nv0);
    nv0 = fmaf(rdlane(acc0, 4 * ib + 3), wA.w, nv0);
    nv1 = fmaf(rdlane(acc1, 4 * ib + 0), wA.x, nv1);
    nv1 = fmaf(rdlane(acc1, 4 * ib + 1), wA.y, nv1);
    nv1 = fmaf(rdlane(acc1, 4 * ib + 2), wA.z, nv1);
    nv1 = fmaf(rdlane(acc1, 4 * ib + 3), wA.w, nv1);
  }

  // --- ctx = [self | nv0 | nv1] @ w1 + b1 (self row uniform from v1ws) ---
  float ctx = b1[lane];
  const float* w1row = &Lw1T[lane * 196];
  const float* selfp = vbase + 32 * 64;
#pragma unroll
  for (int ib = 0; ib < 16; ++ib) {
    const float4 wS = *(const float4*)&w1row[4 * ib];
    const float4 wN0 = *(const float4*)&w1row[64 + 4 * ib];
    const float4 wN1 = *(const float4*)&w1row[128 + 4 * ib];
    const float4 xs = *(const float4*)(selfp + 4 * ib);
    ctx = fmaf(xs.x, wS.x, ctx); ctx = fmaf(xs.y, wS.y, ctx);
    ctx = fmaf(xs.z, wS.z, ctx); ctx = fmaf(xs.w, wS.w, ctx);
    ctx = fmaf(rdlane(nv0, 4 * ib + 0), wN0.x, ctx);
    ctx = fmaf(rdlane(nv0, 4 * ib + 1), wN0.y, ctx);
    ctx = fmaf(rdlane(nv0, 4 * ib + 2), wN0.z, ctx);
    ctx = fmaf(rdlane(nv0, 4 * ib + 3), wN0.w, ctx);
    ctx = fmaf(rdlane(nv1, 4 * ib + 0), wN1.x, ctx);
    ctx = fmaf(rdlane(nv1, 4 * ib + 1), wN1.y, ctx);
    ctx = fmaf(rdlane(nv1, 4 * ib + 2), wN1.z, ctx);
    ctx = fmaf(rdlane(nv1, 4 * ib + 3), wN1.w, ctx);
  }

  // --- q = u @ wq + bq (u row uniform) ---
  float q = bq[lane];
  const float* qrow = &LqT[lane * 68];
#pragma unroll
  for (int ib = 0; ib < 16; ++ib) {
    const float4 wQ = *(const float4*)&qrow[4 * ib];
    const float4 xu = *(const float4*)(user_emb + (size_t)uid * 64 + 4 * ib);
    q = fmaf(xu.x, wQ.x, q); q = fmaf(xu.y, wQ.y, q);
    q = fmaf(xu.z, wQ.z, q); q = fmaf(xu.w, wQ.w, q);
  }

  // --- K/V for 10 candidates (tk rows uniform; wk/wv reads shared) ---
  float kk[10], vv[10];
  const float bkv = bk[lane], bvv = bv[lane];
#pragma unroll
  for (int k = 0; k < 10; ++k) { kk[k] = bkv; vv[k] = bvv; }
  const float* krow = &LkT[lane * 68];
  const float* vrow = &LvT[lane * 68];
#pragma unroll
  for (int ib = 0; ib < 16; ++ib) {
    const float4 wK = *(const float4*)&krow[4 * ib];
    const float4 wV = *(const float4*)&vrow[4 * ib];
#pragma unroll
    for (int k = 0; k < 10; ++k) {
      const float4 xt = *(const float4*)(ent_emb + (size_t)tkid[k] * 64 + 4 * ib);
      kk[k] = fmaf(xt.x, wK.x, kk[k]); kk[k] = fmaf(xt.y, wK.y, kk[k]);
      kk[k] = fmaf(xt.z, wK.z, kk[k]); kk[k] = fmaf(xt.w, wK.w, kk[k]);
      vv[k] = fmaf(xt.x, wV.x, vv[k]); vv[k] = fmaf(xt.y, wV.y, vv[k]);
      vv[k] = fmaf(xt.z, wV.z, vv[k]); vv[k] = fmaf(xt.w, wV.w, vv[k]);
    }
  }

  float lg[10];
#pragma unroll
  for (int k = 0; k < 10; ++k) lg[k] = wave_sum64(q * kk[k]) * 0.125f;  // 1/sqrt(64)
  float m = lg[0];
#pragma unroll
  for (int k = 1; k < 10; ++k) m = fmaxf(m, lg[k]);
  float den = 0.f;
  float att[10];
#pragma unroll
  for (int k = 0; k < 10; ++k) { att[k] = expf(lg[k] - m); den += att[k]; }
  const float invden = 1.0f / den;
  float uatt = 0.f;
#pragma unroll
  for (int k = 0; k < 10; ++k) uatt = fmaf(att[k] * invden, vv[k], uatt);

  const float sc = wave_sum64(uatt * ctx + ctx * w_s[lane]);
  if (lane == 0) out[b] = sc + b_s[0];
}

extern "C" void kernel_launch(void* const* d_in, const int* in_sizes, int n_in,
                              void* d_out, int out_size, void* d_ws, size_t ws_size,
                              hipStream_t stream) {
  const int* relations     = (const int*)d_in[0];
  const int* entity_pairs  = (const int*)d_in[1];
  const int* train_edges   = (const int*)d_in[2];
  const int* user_ids      = (const int*)d_in[3];
  const int* top_k_ids     = (const int*)d_in[4];
  const int* entity2edges  = (const int*)d_in[5];
  const int* edge2entities = (const int*)d_in[6];
  const int* edge2relation = (const int*)d_in[7];
  const float* ent_emb  = (const float*)d_in[8];
  const float* rel_emb  = (const float*)d_in[9];
  const float* user_emb = (const float*)d_in[10];
  const float* w_ent0 = (const float*)d_in[11];
  const float* b_ent0 = (const float*)d_in[12];
  const float* w0     = (const float*)d_in[13];
  const float* b0     = (const float*)d_in[14];
  const float* w_ent1 = (const float*)d_in[15];
  const float* b_ent1 = (const float*)d_in[16];
  const float* w1     = (const float*)d_in[17];
  const float* b1     = (const float*)d_in[18];
  const float* wq  = (const float*)d_in[19];
  const float* bq  = (const float*)d_in[20];
  const float* wk  = (const float*)d_in[21];
  const float* bk  = (const float*)d_in[22];
  const float* wv  = (const float*)d_in[23];
  const float* bv  = (const float*)d_in[24];
  const float* w_s = (const float*)d_in[25];
  const float* b_s = (const float*)d_in[26];

  const int bs = in_sizes[0];
  const int n_items = bs * 33;
  float* v1ws = (float*)d_ws;  // n_items * 64 floats (~8.7 MB)

  // 256 blocks x 16 waves: 8448 groups = 2/wave + 1 extra on wave0 of each block.
  k_agg_hop<<<dim3(256), dim3(1024), 25152 * sizeof(float), stream>>>(
      relations, entity_pairs, train_edges, entity2edges, edge2entities,
      edge2relation, ent_emb, rel_emb, w_ent0, b_ent0, w0, b0, v1ws, n_items);

  k_ctx_score<<<dim3((bs + 15) / 16), dim3(1024), 34048 * sizeof(float), stream>>>(
      entity_pairs, train_edges, user_ids, top_k_ids, entity2edges,
      ent_emb, user_emb, w_ent1, b_ent1, w1, b1, wq, bq, wk, bk, wv, bv,
      w_s, b_s, v1ws, (float*)d_out, bs);
}